// Round 7
// baseline (312.783 us; speedup 1.0000x reference)
//
#include <hip/hip_runtime.h>

#define EMB 128
#define W1LD 532   // PRED_IN
#define KP 160     // padded K for MFMA (138 -> 160)
#define ST 264     // LDS row stride (u16) in node path
#define BSH 8      // bucket shift: 256 nodes per bucket
#define BNODES 256
#define EPB 4096   // edges per sort block

typedef unsigned long long u64;
typedef unsigned int u32;
typedef unsigned short u16;
typedef __attribute__((ext_vector_type(8))) short short8;
typedef __attribute__((ext_vector_type(4))) float f32x4;
typedef _Float16 h2 __attribute__((ext_vector_type(2)));

__device__ __forceinline__ u16 f2bf(float x) {
    unsigned u = __float_as_uint(x);
    unsigned r = (u + 0x7fffu + ((u >> 16) & 1u)) >> 16;
    return (u16)r;
}
__device__ __forceinline__ u16 f2h(float x) {
    union { _Float16 h; u16 u; } c; c.h = (_Float16)x; return c.u;
}
__device__ __forceinline__ h2 u2h(unsigned u) {
    union { unsigned u; h2 h; } c; c.u = u; return c.h;
}

// packed f16 triple-add + relu + dot2 accumulate (8 elems = 4 u32 lanes)
__device__ __forceinline__ float ep8(const uint4& ua, const uint4& ub,
                                     const uint4& ur, const uint4& uw, float s) {
    const h2 z = {(_Float16)0.0f, (_Float16)0.0f};
#if __has_builtin(__builtin_amdgcn_fdot2)
#define FDOT2(x, w, s) __builtin_amdgcn_fdot2(x, w, s, false)
#else
#define FDOT2(x, w, s) (s + (float)x[0] * (float)w[0] + (float)x[1] * (float)w[1])
#endif
#define EP1(c)                                                         \
    {                                                                  \
        h2 x = u2h(ua.c) + u2h(ur.c) + u2h(ub.c);                      \
        x = __builtin_elementwise_max(x, z);                           \
        h2 w = u2h(uw.c);                                              \
        s = FDOT2(x, w, s);                                            \
    }
    EP1(x) EP1(y) EP1(z) EP1(w)
#undef EP1
#undef FDOT2
    return s;
}

// ---------------------------------------------------------------------------
// khist: per-sort-block RAW bucket histograms, both directions.
// hist layout: [row][sb], row = dir*NBKT + bkt  (row-major, NSB stride)
// ---------------------------------------------------------------------------
__global__ __launch_bounds__(1024) void khist(
    const int* __restrict__ h_id, const int* __restrict__ t_id,
    u32* __restrict__ hist, int E, int NBKT, int NSB)
{
    __shared__ u32 lh[1024];
    const int t = threadIdx.x, sb = blockIdx.x;
    const int rows = 2 * NBKT;
    for (int i = t; i < rows; i += 1024) lh[i] = 0;
    __syncthreads();
    const int base = sb * EPB;
#pragma unroll
    for (int c = 0; c < EPB / 1024; c++) {
        int e = base + c * 1024 + t;
        if (e < E) {
            atomicAdd(&lh[t_id[e] >> BSH], 1u);
            atomicAdd(&lh[NBKT + (h_id[e] >> BSH)], 1u);
        }
    }
    __syncthreads();
    for (int i = t; i < rows; i += 1024) hist[(size_t)i * NSB + sb] = lh[i];
}

// ---------------------------------------------------------------------------
// kplace2: fused scan+place. Each block recomputes (a) its per-row prefix
// over earlier sort-blocks and (b) the row-base offsets via an LDS scan of
// row totals (hist stays RAW; reads are L2-resident broadcast). Placement
// cursors in LDS -> zero global atomics. Requires 2*NBKT <= 1024.
// perm_t (u32): h | (t&255)<<17.  perm_e (u64): h | t<<17 | r<<34 | e<<43.
// ---------------------------------------------------------------------------
__global__ __launch_bounds__(1024) void kplace2(
    const int* __restrict__ h_id, const int* __restrict__ r_id,
    const int* __restrict__ t_id,
    const u32* __restrict__ hist, u32* __restrict__ bstart,
    u32* __restrict__ perm_t, u64* __restrict__ perm_e,
    int E, int NBKT, int NSB)
{
    __shared__ u32 sc[1024];
    __shared__ u32 exl[1024];
    __shared__ u32 cur[1024];
    const int t = threadIdx.x, sb = blockIdx.x;
    const int rows = 2 * NBKT;

    u32 myTot = 0, myPre = 0;
    if (t < rows) {
        const u32* hr = hist + (size_t)t * NSB;
        for (int s = 0; s < NSB; s++) {
            u32 v = hr[s];
            myTot += v;
            myPre += (s < sb) ? v : 0;
        }
    }
    sc[t] = (t < rows) ? myTot : 0;
    __syncthreads();
    for (int o = 1; o < 1024; o <<= 1) {      // Hillis-Steele inclusive scan
        u32 x = (t >= o) ? sc[t - o] : 0;
        __syncthreads();
        sc[t] += x;
        __syncthreads();
    }
    exl[t] = sc[t] - ((t < rows) ? myTot : 0);  // exclusive
    __syncthreads();
    if (t < rows) {
        const int b0 = (t < NBKT) ? 0 : NBKT;
        u32 base = exl[t] - ((t < NBKT) ? 0u : exl[NBKT]);
        cur[t] = base + myPre;
        if (sb == 0) {
            const int seg = (t < NBKT) ? 0 : (NBKT + 1);
            bstart[seg + (t - b0)] = base;
            if (t == b0) bstart[seg + NBKT] = (u32)E;
        }
    }
    __syncthreads();
    const int ebase = sb * EPB;
#pragma unroll
    for (int c = 0; c < EPB / 1024; c++) {
        int e = ebase + c * 1024 + t;
        if (e < E) {
            int tt = t_id[e], h = h_id[e], r = r_id[e];
            u32 pt = atomicAdd(&cur[tt >> BSH], 1u);
            perm_t[pt] = (u32)h | ((u32)(tt & (BNODES - 1)) << 17);
            u32 ph = atomicAdd(&cur[NBKT + (h >> BSH)], 1u);
            perm_e[ph] = (u64)h | ((u64)tt << 17) | ((u64)r << 34)
                       | ((u64)e << 43);
        }
    }
}

// ---------------------------------------------------------------------------
// kscat<ROUND>: LDS-accumulated scatter-mean, one block per (dir,bucket).
// pack: [x*2^20:26][y*2^20:26][cnt:12]. ROUND=1 src=topic (+prep blocks);
// ROUND=2 src = dde1f (t-dir) / dde3f (h-dir).
// ---------------------------------------------------------------------------
__device__ __forceinline__ void scat_bucket(
    int d, int b, const u32* perm_t, const u64* perm_e, const u32* bstart,
    const float* srcv, float* out, int N, int NBKT, u64* acc)
{
    const int t = threadIdx.x;
    for (int i = t; i < BNODES; i += 256) acc[i] = 0;
    __syncthreads();
    const u32 s0 = bstart[d * (NBKT + 1) + b];
    const u32 s1 = bstart[d * (NBKT + 1) + b + 1];
    if (d == 0) {
        for (u32 i = s0 + t; i < s1; i += 256) {
            u32 rec  = perm_t[i];
            u32 src  = rec & 0x1FFFFu;
            u32 slot = rec >> 17;
            float2 v = *(const float2*)(srcv + 2 * src);
            u64 p = (u64)__float2uint_rn(v.x * 1048576.0f)
                  | ((u64)__float2uint_rn(v.y * 1048576.0f) << 26)
                  | (1ull << 52);
            atomicAdd(&acc[slot], p);
        }
    } else {
        for (u32 i = s0 + t; i < s1; i += 256) {
            u64 rec  = perm_e[i];
            u32 src  = (u32)(rec >> 17) & 0x1FFFFu;   // t
            u32 slot = (u32)rec & (BNODES - 1);        // h & 255
            float2 v = *(const float2*)(srcv + 2 * src);
            u64 p = (u64)__float2uint_rn(v.x * 1048576.0f)
                  | ((u64)__float2uint_rn(v.y * 1048576.0f) << 26)
                  | (1ull << 52);
            atomicAdd(&acc[slot], p);
        }
    }
    __syncthreads();
    for (int i = t; i < BNODES; i += 256) {
        int node = b * BNODES + i;
        if (node < N) {
            u64 a = acc[i];
            float cnt = (float)(u32)(a >> 52);
            float inv = (1.0f / 1048576.0f) / fmaxf(cnt, 1.0f);
            float2 m;
            m.x = (float)(u32)(a & 0x3FFFFFFu) * inv;
            m.y = (float)(u32)((a >> 26) & 0x3FFFFFFu) * inv;
            *(float2*)(out + 2 * node) = m;
        }
    }
}

__device__ __forceinline__ void prep_block(
    int pb, const float* W1, const float* q, const float* rel,
    const float* b1, const float* W2,
    u16* WBF, float* qWb, u16* W2h, u16* Rbf, float* v /*LDS 128*/)
{
    const int t = threadIdx.x;
    if (pb < KP) {
        int k = pb, n = t;
        float val = 0.0f;
        if (k < 138) {
            val = (n < 128) ? W1[(size_t)n * W1LD + 128 + k]
                            : W1[(size_t)(n - 128) * W1LD + 394 + k];
        }
        int kstep = k >> 5, quad = (k >> 3) & 3, j = k & 7;
        WBF[(((size_t)(kstep * 4 + quad) * 256 + n) << 3) + j] = f2bf(val);
        return;
    }
    int b = pb - KP;   // 0 -> qWb + W2h ; 1.. -> relation b-1
    if (t < EMB) v[t] = (b == 0) ? q[t] : rel[(size_t)(b - 1) * EMB + t];
    __syncthreads();
    if (t < EMB) {
        const float* w = W1 + (size_t)t * W1LD + (b == 0 ? 0 : 266);
        float s = 0.0f;
#pragma unroll
        for (int k = 0; k < EMB; k += 4) {
            float4 wv = *(const float4*)(w + k);
            s += wv.x * v[k] + wv.y * v[k + 1] + wv.z * v[k + 2] + wv.w * v[k + 3];
        }
        if (b == 0) { qWb[t] = s + b1[t]; W2h[t] = f2h(W2[t]); }
        else        Rbf[(size_t)(b - 1) * EMB + t] = f2h(s);
    }
}

template<int ROUND>
__global__ __launch_bounds__(256) void kscat(
    const u32* __restrict__ perm_t, const u64* __restrict__ perm_e,
    const u32* __restrict__ bstart,
    const float* __restrict__ topic,
    const float* __restrict__ src_t, const float* __restrict__ src_h,
    float* __restrict__ out_t, float* __restrict__ out_h,
    const float* __restrict__ W1, const float* __restrict__ q,
    const float* __restrict__ rel, const float* __restrict__ b1,
    const float* __restrict__ W2,
    u16* __restrict__ WBF, float* __restrict__ qWb,
    u16* __restrict__ W2h, u16* __restrict__ Rbf,
    int N, int NBKT, int NREL)
{
    const int bid = blockIdx.x;
    if (bid < 2 * NBKT) {
        __shared__ u64 acc[BNODES];
        const int d = (bid < NBKT) ? 0 : 1;
        const float* srcv = (ROUND == 1) ? topic : (d ? src_h : src_t);
        scat_bucket(d, bid - d * NBKT, perm_t, perm_e, bstart,
                    srcv, d ? out_h : out_t, N, NBKT, acc);
        return;
    }
    if (ROUND != 1) return;
    __shared__ float v[EMB];
    prep_block(bid - 2 * NBKT, W1, q, rel, b1, W2, WBF, qWb, W2h, Rbf, v);
}

// ---------------------------------------------------------------------------
// k2b_node: node MFMA GEMM with FULL tails; outputs A/B in f16.
// ---------------------------------------------------------------------------
__global__ __launch_bounds__(256) void k2b_node(
    const float* __restrict__ ent, const float* __restrict__ nte,
    const float* __restrict__ topic,
    const float* __restrict__ dde1f, const float* __restrict__ dde2f,
    const float* __restrict__ dde3f, const float* __restrict__ dde4f,
    const u16* __restrict__ WBF, const float* __restrict__ qWb,
    u16* __restrict__ A, u16* __restrict__ B,
    int NT, int N)
{
    __shared__ __align__(16) u16 lds[32 * ST];
    const int t = threadIdx.x;
    const int lane = t & 63;
    const int w    = t >> 6;
    const int ln15 = lane & 15;
    const int quad = lane >> 4;
    const int m0   = (w & 1) * 16;
    const int n0   = (w >> 1) * 128;
    const int nblk = blockIdx.x * 32;

    {   // stage dense features as bf16 (MFMA input)
        int m  = t >> 3;
        int kq = (t & 7) << 4;
        int gn = nblk + m;
        const float* src = (gn < N) ? ((gn < NT) ? ent + (size_t)gn * EMB + kq
                                                 : nte + kq)
                                    : nte;
        u16 pk[16];
#pragma unroll
        for (int p = 0; p < 4; p++) {
            float4 v = (gn < N) ? *(const float4*)(src + 4 * p)
                                : make_float4(0.f, 0.f, 0.f, 0.f);
            pk[4 * p + 0] = f2bf(v.x); pk[4 * p + 1] = f2bf(v.y);
            pk[4 * p + 2] = f2bf(v.z); pk[4 * p + 3] = f2bf(v.w);
        }
        *(uint4*)&lds[m * ST + kq]     = *(uint4*)&pk[0];
        *(uint4*)&lds[m * ST + kq + 8] = *(uint4*)&pk[8];
    }
    // tail: topic(2) + dde1..4 (8) at k=128..137; 138..159 zero
    if (t < 32) {
        int gn = nblk + t;
        if (gn < N) {
            float2 tp = *(const float2*)(topic + 2 * gn);
            float2 d1 = *(const float2*)(dde1f + 2 * gn);
            float2 d2 = *(const float2*)(dde2f + 2 * gn);
            float2 d3 = *(const float2*)(dde3f + 2 * gn);
            float2 d4 = *(const float2*)(dde4f + 2 * gn);
            lds[t * ST + 128] = f2bf(tp.x); lds[t * ST + 129] = f2bf(tp.y);
            lds[t * ST + 130] = f2bf(d1.x); lds[t * ST + 131] = f2bf(d1.y);
            lds[t * ST + 132] = f2bf(d2.x); lds[t * ST + 133] = f2bf(d2.y);
            lds[t * ST + 134] = f2bf(d3.x); lds[t * ST + 135] = f2bf(d3.y);
            lds[t * ST + 136] = f2bf(d4.x); lds[t * ST + 137] = f2bf(d4.y);
        } else {
#pragma unroll
            for (int z = 128; z < 138; z++) lds[t * ST + z] = 0;
        }
#pragma unroll
        for (int z = 138; z < KP; z++) lds[t * ST + z] = 0;
    }
    __syncthreads();

    f32x4 acc[8];
#pragma unroll
    for (int i = 0; i < 8; i++) acc[i] = (f32x4){0.f, 0.f, 0.f, 0.f};

    const u16* wbbase = WBF + (((size_t)quad * 256 + n0 + ln15) << 3);
#pragma unroll
    for (int ks = 0; ks < 5; ks++) {
        short8 a = *(const short8*)&lds[(m0 + ln15) * ST + ks * 32 + quad * 8];
        const u16* wb = wbbase + ((size_t)ks * 4 * 256 * 8);
#pragma unroll
        for (int nt = 0; nt < 8; nt++) {
            short8 b = *(const short8*)(wb + (nt << 7));
            acc[nt] = __builtin_amdgcn_mfma_f32_16x16x32_bf16(a, b, acc[nt], 0, 0, 0);
        }
    }

    __syncthreads();   // all a-frag reads done before overwrite
#pragma unroll
    for (int nt = 0; nt < 8; nt++) {
        int c = n0 + nt * 16 + ln15;
        float qv = (n0 == 0) ? qWb[c] : 0.0f;
#pragma unroll
        for (int r = 0; r < 4; r++) {
            int row = m0 + quad * 4 + r;
            lds[row * ST + c] = f2h(acc[nt][r] + qv);   // f16 output
        }
    }
    __syncthreads();
    {
        int m  = t >> 3;
        int c0 = (t & 7) * 32;
        int gn = nblk + m;
        if (gn < N) {
            uint4 v0 = *(uint4*)&lds[m * ST + c0];
            uint4 v1 = *(uint4*)&lds[m * ST + c0 + 8];
            uint4 v2 = *(uint4*)&lds[m * ST + c0 + 16];
            uint4 v3 = *(uint4*)&lds[m * ST + c0 + 24];
            u16* dst = (c0 < 128) ? (A + (size_t)gn * EMB + c0)
                                  : (B + (size_t)gn * EMB + (c0 - 128));
            ((uint4*)dst)[0] = v0;
            ((uint4*)dst)[1] = v1;
            ((uint4*)dst)[2] = v2;
            ((uint4*)dst)[3] = v3;
        }
    }
}

// ---------------------------------------------------------------------------
// K4 sorted, 4-edge unroll: each 16-lane group handles 4 consecutive perm
// entries -> 12 gather loads in flight (MLP) instead of 3. perm order is
// h-bucketed -> A gathers L2-local. f16 packed math.
// ---------------------------------------------------------------------------
__global__ __launch_bounds__(256) void edge_pred_srt4(
    const u64* __restrict__ perm_e,
    const u16* __restrict__ A, const u16* __restrict__ B,
    const u16* __restrict__ Rbf, const u16* __restrict__ W2h,
    const float* __restrict__ b2, float* __restrict__ out, int E)
{
    const int t    = threadIdx.x;
    const int lane = t & 63;
    const int g    = lane >> 4;
    const int k    = lane & 15;
    const int wv   = t >> 6;
    const int i0   = (blockIdx.x * 16 + wv * 4 + g) * 4;

    const uint4 uw = *(const uint4*)(W2h + k * 8);
    const float bb = b2[0];

    u64 rec[4];
    bool val[4];
#pragma unroll
    for (int j = 0; j < 4; j++) {
        val[j] = (i0 + j) < E;
        rec[j] = val[j] ? perm_e[i0 + j] : 0;   // rec=0 -> safe node-0 loads
    }
    uint4 ua[4], ub[4], ur[4];
#pragma unroll
    for (int j = 0; j < 4; j++) {
        u32 h  = (u32)rec[j] & 0x1FFFFu;
        u32 tt = (u32)(rec[j] >> 17) & 0x1FFFFu;
        u32 r  = (u32)(rec[j] >> 34) & 0x1FFu;
        ua[j] = *(const uint4*)(A + (size_t)h * EMB + k * 8);
        ub[j] = *(const uint4*)(B + (size_t)tt * EMB + k * 8);
        ur[j] = *(const uint4*)(Rbf + (size_t)r * EMB + k * 8);
    }
    float s[4];
#pragma unroll
    for (int j = 0; j < 4; j++) s[j] = ep8(ua[j], ub[j], ur[j], uw, 0.0f);
#pragma unroll
    for (int j = 0; j < 4; j++) {
        float v = s[j];
        v += __shfl_xor(v, 1, 64);
        v += __shfl_xor(v, 2, 64);
        v += __shfl_xor(v, 4, 64);
        v += __shfl_xor(v, 8, 64);
        if (k == 0 && val[j]) out[(u32)(rec[j] >> 43)] = v + bb;
    }
}

// K4 fallback (unsorted, f16 math) when workspace can't hold dedicated perm.
__global__ __launch_bounds__(256) void edge_pred_f16(
    const int* __restrict__ h_id, const int* __restrict__ r_id,
    const int* __restrict__ t_id,
    const u16* __restrict__ A, const u16* __restrict__ B,
    const u16* __restrict__ Rbf, const u16* __restrict__ W2h,
    const float* __restrict__ b2, float* __restrict__ out, int E)
{
    const int t    = threadIdx.x;
    const int lane = t & 63;
    const int g    = lane >> 4;
    const int k    = lane & 15;
    const int wv   = t >> 6;
    const int e    = blockIdx.x * 16 + wv * 4 + g;

    const uint4 uw = *(const uint4*)(W2h + k * 8);
    float s = 0.0f;
    if (e < E) {
        const int h = h_id[e], r = r_id[e], tt = t_id[e];
        const uint4 ua = *(const uint4*)(A + (size_t)h * EMB + k * 8);
        const uint4 ub = *(const uint4*)(B + (size_t)tt * EMB + k * 8);
        const uint4 ur = *(const uint4*)(Rbf + (size_t)r * EMB + k * 8);
        s = ep8(ua, ub, ur, uw, 0.0f);
    }
    s += __shfl_xor(s, 1, 64);
    s += __shfl_xor(s, 2, 64);
    s += __shfl_xor(s, 4, 64);
    s += __shfl_xor(s, 8, 64);
    if (k == 0 && e < E) out[e] = s + b2[0];
}

// ---------------------------------------------------------------------------

extern "C" void kernel_launch(void* const* d_in, const int* in_sizes, int n_in,
                              void* d_out, int out_size, void* d_ws, size_t ws_size,
                              hipStream_t stream)
{
    const int*   h_id  = (const int*)d_in[0];
    const int*   r_id  = (const int*)d_in[1];
    const int*   t_id  = (const int*)d_in[2];
    const float* q_emb = (const float*)d_in[3];
    const float* ent   = (const float*)d_in[4];
    const float* rel   = (const float*)d_in[6];
    const float* topic = (const float*)d_in[7];
    const float* nte   = (const float*)d_in[8];
    const float* W1    = (const float*)d_in[9];
    const float* b1    = (const float*)d_in[10];
    const float* W2    = (const float*)d_in[11];
    const float* b2    = (const float*)d_in[12];

    const int E    = in_sizes[0];
    const int NT   = in_sizes[4] / EMB;  // 80000 text entities
    const int N    = in_sizes[7] / 2;    // 100000 total nodes
    const int NREL = in_sizes[6] / EMB;  // 500 relations

    const int NBKT = (N + BNODES - 1) >> BSH;      // 391
    const int NSB  = (E + EPB - 1) / EPB;          // 196

    // persistent layout: [qWb][W2h][Rbf][WBF][dde1..4][Aw][Bw][perm_e?]
    float* qWb  = (float*)d_ws;                      // 128 f32
    u16* W2h    = (u16*)(qWb + EMB);                 // 128 f16
    u16* Rbf    = W2h + EMB;                         // NREL*128 f16
    u16* WBF    = Rbf + (size_t)NREL * EMB;          // KP*256 bf16
    float* dde1f = (float*)(WBF + (size_t)KP * 256); // N float2
    float* dde2f = dde1f + 2 * (size_t)N;
    float* dde3f = dde2f + 2 * (size_t)N;
    float* dde4f = dde3f + 2 * (size_t)N;
    u16* Aw = (u16*)(dde4f + 2 * (size_t)N);         // N*128 f16
    u16* Bw = Aw + (size_t)N * EMB;                  // N*128 f16
    u64* perm_ded = (u64*)(Bw + (size_t)N * EMB);    // E u64 (sorted path)

    // sort scratch aliased into Aw/Bw (dead before k2b_node writes A/B)
    u32* hist   = (u32*)Aw;                          // 2*NBKT*NSB
    u32* bstart = hist + (size_t)2 * NBKT * NSB;     // 2*(NBKT+1)
    u32* perm_t = bstart + 2 * (NBKT + 1);           // E
    u64* perm_alias = (u64*)(((size_t)(perm_t + E) + 7) & ~(size_t)7);

    size_t need_srt = (size_t)((char*)(perm_ded + E) - (char*)d_ws);
    const bool srt = (ws_size >= need_srt) && (E < (1 << 20)) &&
                     (N <= (1 << 17)) && (NREL <= (1 << 9)) &&
                     (2 * NBKT <= 1024);
    u64* perm_e = srt ? perm_ded : perm_alias;

    const int nn = (N + 31) / 32;

    // ---- counting sort (both directions), zero global atomics ----
    khist<<<NSB, 1024, 0, stream>>>(h_id, t_id, hist, E, NBKT, NSB);
    kplace2<<<NSB, 1024, 0, stream>>>(h_id, r_id, t_id, hist, bstart,
                                      perm_t, perm_e, E, NBKT, NSB);

    // ---- scatter round 1 (+ prep) ----
    kscat<1><<<2 * NBKT + KP + 1 + NREL, 256, 0, stream>>>(
        perm_t, perm_e, bstart, topic, nullptr, nullptr, dde1f, dde3f,
        W1, q_emb, rel, b1, W2, WBF, qWb, W2h, Rbf, N, NBKT, NREL);

    // ---- scatter round 2 ----
    kscat<2><<<2 * NBKT, 256, 0, stream>>>(
        perm_t, perm_e, bstart, topic, dde1f, dde3f, dde2f, dde4f,
        W1, q_emb, rel, b1, W2, WBF, qWb, W2h, Rbf, N, NBKT, NREL);

    // ---- node GEMM (overwrites sort scratch; outputs f16 A/B) ----
    k2b_node<<<nn, 256, 0, stream>>>(
        ent, nte, topic, dde1f, dde2f, dde3f, dde4f,
        WBF, qWb, Aw, Bw, NT, N);

    // ---- edge prediction ----
    if (srt) {
        edge_pred_srt4<<<(E + 63) / 64, 256, 0, stream>>>(
            perm_e, Aw, Bw, Rbf, W2h, b2, (float*)d_out, E);
    } else {
        edge_pred_f16<<<(E + 15) / 16, 256, 0, stream>>>(
            h_id, r_id, t_id, Aw, Bw, Rbf, W2h, b2, (float*)d_out, E);
    }
}

// Round 8
// 253.060 us; speedup vs baseline: 1.2360x; 1.2360x over previous
//
#include <hip/hip_runtime.h>

#define EMB 128
#define W1LD 532   // PRED_IN
#define KP 160     // padded K for MFMA (138 -> 160)
#define ST 264     // LDS row stride (u16) in node path
#define BSH 8      // bucket shift: 256 nodes per bucket
#define BNODES 256
#define EPB 4096   // edges per sort block

typedef unsigned long long u64;
typedef unsigned int u32;
typedef unsigned short u16;
typedef __attribute__((ext_vector_type(8))) short short8;
typedef __attribute__((ext_vector_type(4))) float f32x4;
typedef _Float16 h2 __attribute__((ext_vector_type(2)));

__device__ __forceinline__ u16 f2bf(float x) {
    unsigned u = __float_as_uint(x);
    unsigned r = (u + 0x7fffu + ((u >> 16) & 1u)) >> 16;
    return (u16)r;
}
__device__ __forceinline__ u16 f2h(float x) {
    union { _Float16 h; u16 u; } c; c.h = (_Float16)x; return c.u;
}
__device__ __forceinline__ h2 u2h(unsigned u) {
    union { unsigned u; h2 h; } c; c.u = u; return c.h;
}

// packed f16 triple-add + relu + dot2 accumulate (8 elems = 4 u32 lanes)
__device__ __forceinline__ float ep8(const uint4& ua, const uint4& ub,
                                     const uint4& ur, const uint4& uw, float s) {
    const h2 z = {(_Float16)0.0f, (_Float16)0.0f};
#if __has_builtin(__builtin_amdgcn_fdot2)
#define FDOT2(x, w, s) __builtin_amdgcn_fdot2(x, w, s, false)
#else
#define FDOT2(x, w, s) (s + (float)x[0] * (float)w[0] + (float)x[1] * (float)w[1])
#endif
#define EP1(c)                                                         \
    {                                                                  \
        h2 x = u2h(ua.c) + u2h(ur.c) + u2h(ub.c);                      \
        x = __builtin_elementwise_max(x, z);                           \
        h2 w = u2h(uw.c);                                              \
        s = FDOT2(x, w, s);                                            \
    }
    EP1(x) EP1(y) EP1(z) EP1(w)
#undef EP1
#undef FDOT2
    return s;
}

// ---------------------------------------------------------------------------
// khist: per-sort-block RAW bucket histograms, both directions.
// hist layout: [row][sb], row = dir*NBKT + bkt  (row-major, NSB stride)
// ---------------------------------------------------------------------------
__global__ __launch_bounds__(1024) void khist(
    const int* __restrict__ h_id, const int* __restrict__ t_id,
    u32* __restrict__ hist, int E, int NBKT, int NSB)
{
    __shared__ u32 lh[1024];
    const int t = threadIdx.x, sb = blockIdx.x;
    const int rows = 2 * NBKT;
    for (int i = t; i < rows; i += 1024) lh[i] = 0;
    __syncthreads();
    const int base = sb * EPB;
#pragma unroll
    for (int c = 0; c < EPB / 1024; c++) {
        int e = base + c * 1024 + t;
        if (e < E) {
            atomicAdd(&lh[t_id[e] >> BSH], 1u);
            atomicAdd(&lh[NBKT + (h_id[e] >> BSH)], 1u);
        }
    }
    __syncthreads();
    for (int i = t; i < rows; i += 1024) hist[(size_t)i * NSB + sb] = lh[i];
}

// ---------------------------------------------------------------------------
// kscanA: per-row exclusive scan over sort-blocks (in place) + row totals.
// Grid = 2*NBKT rows, 256 threads; requires NSB <= 256.
// ---------------------------------------------------------------------------
__global__ __launch_bounds__(256) void kscanA(
    u32* __restrict__ hist, u32* __restrict__ tot, int NSB)
{
    __shared__ u32 s[256];
    const int t = threadIdx.x, row = blockIdx.x;
    u32 v = (t < NSB) ? hist[(size_t)row * NSB + t] : 0;
    s[t] = v;
    __syncthreads();
    for (int o = 1; o < 256; o <<= 1) {
        u32 x = (t >= o) ? s[t - o] : 0;
        __syncthreads();
        s[t] += x;
        __syncthreads();
    }
    if (t < NSB) hist[(size_t)row * NSB + t] = s[t] - v;   // exclusive prefix
    if (t == 255) tot[row] = s[255];
}

// ---------------------------------------------------------------------------
// kbase: single block. Segmented scan of row totals -> per-row global base
// (segment 0 = t-dir rows [0,NBKT), segment 1 = h-dir rows). Also writes
// bstart (bucket bases + terminator) for the scatter kernels.
// Requires 2*NBKT <= 1024.
// ---------------------------------------------------------------------------
__global__ __launch_bounds__(1024) void kbase(
    const u32* __restrict__ tot, u32* __restrict__ base,
    u32* __restrict__ bstart, int NBKT, int E)
{
    __shared__ u32 sc[1024];
    const int t = threadIdx.x;
    const int rows = 2 * NBKT;
    u32 v = (t < rows) ? tot[t] : 0;
    sc[t] = v;
    __syncthreads();
    for (int o = 1; o < 1024; o <<= 1) {
        u32 x = (t >= o) ? sc[t - o] : 0;
        __syncthreads();
        sc[t] += x;
        __syncthreads();
    }
    __syncthreads();
    if (t < rows) {
        u32 excl = sc[t] - v;
        u32 seg0 = (t >= NBKT) ? (sc[NBKT - 1 + 1 - 1] - 0) : 0;  // excl[NBKT]
        // excl[NBKT] = inclusive sum of rows [0,NBKT) = sc[NBKT-1]
        u32 segoff = (t >= NBKT) ? sc[NBKT - 1] : 0;
        (void)seg0;
        u32 b = excl - segoff;
        base[t] = b;
        const int seg = (t < NBKT) ? 0 : (NBKT + 1);
        const int b0  = (t < NBKT) ? 0 : NBKT;
        bstart[seg + (t - b0)] = b;
        if (t == b0) bstart[seg + NBKT] = (u32)E;
    }
}

// ---------------------------------------------------------------------------
// kplace: bucket-major permutations; cursor init is O(1) per row
// (base[row] + per-row exclusive prefix from hist). LDS cursors -> zero
// global atomics. perm_t (u32): h | (t&255)<<17.
// perm_e (u64): h | t<<17 | r<<34 | e<<43.
// ---------------------------------------------------------------------------
__global__ __launch_bounds__(1024) void kplace(
    const int* __restrict__ h_id, const int* __restrict__ r_id,
    const int* __restrict__ t_id,
    const u32* __restrict__ hist, const u32* __restrict__ base,
    u32* __restrict__ perm_t, u64* __restrict__ perm_e,
    int E, int NBKT, int NSB)
{
    __shared__ u32 cur[1024];
    const int t = threadIdx.x, sb = blockIdx.x;
    const int rows = 2 * NBKT;
    if (t < rows) cur[t] = base[t] + hist[(size_t)t * NSB + sb];
    __syncthreads();
    const int ebase = sb * EPB;
#pragma unroll
    for (int c = 0; c < EPB / 1024; c++) {
        int e = ebase + c * 1024 + t;
        if (e < E) {
            int tt = t_id[e], h = h_id[e], r = r_id[e];
            u32 pt = atomicAdd(&cur[tt >> BSH], 1u);
            perm_t[pt] = (u32)h | ((u32)(tt & (BNODES - 1)) << 17);
            u32 ph = atomicAdd(&cur[NBKT + (h >> BSH)], 1u);
            perm_e[ph] = (u64)h | ((u64)tt << 17) | ((u64)r << 34)
                       | ((u64)e << 43);
        }
    }
}

// ---------------------------------------------------------------------------
// kscat<ROUND>: LDS-accumulated scatter-mean, one block per (dir,bucket).
// pack: [x*2^20:26][y*2^20:26][cnt:12]. ROUND=1 src=topic (+prep blocks);
// ROUND=2 src = dde1f (t-dir) / dde3f (h-dir).
// ---------------------------------------------------------------------------
__device__ __forceinline__ void scat_bucket(
    int d, int b, const u32* perm_t, const u64* perm_e, const u32* bstart,
    const float* srcv, float* out, int N, int NBKT, u64* acc)
{
    const int t = threadIdx.x;
    for (int i = t; i < BNODES; i += 256) acc[i] = 0;
    __syncthreads();
    const u32 s0 = bstart[d * (NBKT + 1) + b];
    const u32 s1 = bstart[d * (NBKT + 1) + b + 1];
    if (d == 0) {
        for (u32 i = s0 + t; i < s1; i += 256) {
            u32 rec  = perm_t[i];
            u32 src  = rec & 0x1FFFFu;
            u32 slot = rec >> 17;
            float2 v = *(const float2*)(srcv + 2 * src);
            u64 p = (u64)__float2uint_rn(v.x * 1048576.0f)
                  | ((u64)__float2uint_rn(v.y * 1048576.0f) << 26)
                  | (1ull << 52);
            atomicAdd(&acc[slot], p);
        }
    } else {
        for (u32 i = s0 + t; i < s1; i += 256) {
            u64 rec  = perm_e[i];
            u32 src  = (u32)(rec >> 17) & 0x1FFFFu;   // t
            u32 slot = (u32)rec & (BNODES - 1);        // h & 255
            float2 v = *(const float2*)(srcv + 2 * src);
            u64 p = (u64)__float2uint_rn(v.x * 1048576.0f)
                  | ((u64)__float2uint_rn(v.y * 1048576.0f) << 26)
                  | (1ull << 52);
            atomicAdd(&acc[slot], p);
        }
    }
    __syncthreads();
    for (int i = t; i < BNODES; i += 256) {
        int node = b * BNODES + i;
        if (node < N) {
            u64 a = acc[i];
            float cnt = (float)(u32)(a >> 52);
            float inv = (1.0f / 1048576.0f) / fmaxf(cnt, 1.0f);
            float2 m;
            m.x = (float)(u32)(a & 0x3FFFFFFu) * inv;
            m.y = (float)(u32)((a >> 26) & 0x3FFFFFFu) * inv;
            *(float2*)(out + 2 * node) = m;
        }
    }
}

__device__ __forceinline__ void prep_block(
    int pb, const float* W1, const float* q, const float* rel,
    const float* b1, const float* W2,
    u16* WBF, float* qWb, u16* W2h, u16* Rbf, float* v /*LDS 128*/)
{
    const int t = threadIdx.x;
    if (pb < KP) {
        int k = pb, n = t;
        float val = 0.0f;
        if (k < 138) {
            val = (n < 128) ? W1[(size_t)n * W1LD + 128 + k]
                            : W1[(size_t)(n - 128) * W1LD + 394 + k];
        }
        int kstep = k >> 5, quad = (k >> 3) & 3, j = k & 7;
        WBF[(((size_t)(kstep * 4 + quad) * 256 + n) << 3) + j] = f2bf(val);
        return;
    }
    int b = pb - KP;   // 0 -> qWb + W2h ; 1.. -> relation b-1
    if (t < EMB) v[t] = (b == 0) ? q[t] : rel[(size_t)(b - 1) * EMB + t];
    __syncthreads();
    if (t < EMB) {
        const float* w = W1 + (size_t)t * W1LD + (b == 0 ? 0 : 266);
        float s = 0.0f;
#pragma unroll
        for (int k = 0; k < EMB; k += 4) {
            float4 wv = *(const float4*)(w + k);
            s += wv.x * v[k] + wv.y * v[k + 1] + wv.z * v[k + 2] + wv.w * v[k + 3];
        }
        if (b == 0) { qWb[t] = s + b1[t]; W2h[t] = f2h(W2[t]); }
        else        Rbf[(size_t)(b - 1) * EMB + t] = f2h(s);
    }
}

template<int ROUND>
__global__ __launch_bounds__(256) void kscat(
    const u32* __restrict__ perm_t, const u64* __restrict__ perm_e,
    const u32* __restrict__ bstart,
    const float* __restrict__ topic,
    const float* __restrict__ src_t, const float* __restrict__ src_h,
    float* __restrict__ out_t, float* __restrict__ out_h,
    const float* __restrict__ W1, const float* __restrict__ q,
    const float* __restrict__ rel, const float* __restrict__ b1,
    const float* __restrict__ W2,
    u16* __restrict__ WBF, float* __restrict__ qWb,
    u16* __restrict__ W2h, u16* __restrict__ Rbf,
    int N, int NBKT, int NREL)
{
    const int bid = blockIdx.x;
    if (bid < 2 * NBKT) {
        __shared__ u64 acc[BNODES];
        const int d = (bid < NBKT) ? 0 : 1;
        const float* srcv = (ROUND == 1) ? topic : (d ? src_h : src_t);
        scat_bucket(d, bid - d * NBKT, perm_t, perm_e, bstart,
                    srcv, d ? out_h : out_t, N, NBKT, acc);
        return;
    }
    if (ROUND != 1) return;
    __shared__ float v[EMB];
    prep_block(bid - 2 * NBKT, W1, q, rel, b1, W2, WBF, qWb, W2h, Rbf, v);
}

// ---------------------------------------------------------------------------
// k2b_node: node MFMA GEMM with FULL tails; outputs A/B in f16.
// ---------------------------------------------------------------------------
__global__ __launch_bounds__(256) void k2b_node(
    const float* __restrict__ ent, const float* __restrict__ nte,
    const float* __restrict__ topic,
    const float* __restrict__ dde1f, const float* __restrict__ dde2f,
    const float* __restrict__ dde3f, const float* __restrict__ dde4f,
    const u16* __restrict__ WBF, const float* __restrict__ qWb,
    u16* __restrict__ A, u16* __restrict__ B,
    int NT, int N)
{
    __shared__ __align__(16) u16 lds[32 * ST];
    const int t = threadIdx.x;
    const int lane = t & 63;
    const int w    = t >> 6;
    const int ln15 = lane & 15;
    const int quad = lane >> 4;
    const int m0   = (w & 1) * 16;
    const int n0   = (w >> 1) * 128;
    const int nblk = blockIdx.x * 32;

    {   // stage dense features as bf16 (MFMA input)
        int m  = t >> 3;
        int kq = (t & 7) << 4;
        int gn = nblk + m;
        const float* src = (gn < N) ? ((gn < NT) ? ent + (size_t)gn * EMB + kq
                                                 : nte + kq)
                                    : nte;
        u16 pk[16];
#pragma unroll
        for (int p = 0; p < 4; p++) {
            float4 v = (gn < N) ? *(const float4*)(src + 4 * p)
                                : make_float4(0.f, 0.f, 0.f, 0.f);
            pk[4 * p + 0] = f2bf(v.x); pk[4 * p + 1] = f2bf(v.y);
            pk[4 * p + 2] = f2bf(v.z); pk[4 * p + 3] = f2bf(v.w);
        }
        *(uint4*)&lds[m * ST + kq]     = *(uint4*)&pk[0];
        *(uint4*)&lds[m * ST + kq + 8] = *(uint4*)&pk[8];
    }
    // tail: topic(2) + dde1..4 (8) at k=128..137; 138..159 zero
    if (t < 32) {
        int gn = nblk + t;
        if (gn < N) {
            float2 tp = *(const float2*)(topic + 2 * gn);
            float2 d1 = *(const float2*)(dde1f + 2 * gn);
            float2 d2 = *(const float2*)(dde2f + 2 * gn);
            float2 d3 = *(const float2*)(dde3f + 2 * gn);
            float2 d4 = *(const float2*)(dde4f + 2 * gn);
            lds[t * ST + 128] = f2bf(tp.x); lds[t * ST + 129] = f2bf(tp.y);
            lds[t * ST + 130] = f2bf(d1.x); lds[t * ST + 131] = f2bf(d1.y);
            lds[t * ST + 132] = f2bf(d2.x); lds[t * ST + 133] = f2bf(d2.y);
            lds[t * ST + 134] = f2bf(d3.x); lds[t * ST + 135] = f2bf(d3.y);
            lds[t * ST + 136] = f2bf(d4.x); lds[t * ST + 137] = f2bf(d4.y);
        } else {
#pragma unroll
            for (int z = 128; z < 138; z++) lds[t * ST + z] = 0;
        }
#pragma unroll
        for (int z = 138; z < KP; z++) lds[t * ST + z] = 0;
    }
    __syncthreads();

    f32x4 acc[8];
#pragma unroll
    for (int i = 0; i < 8; i++) acc[i] = (f32x4){0.f, 0.f, 0.f, 0.f};

    const u16* wbbase = WBF + (((size_t)quad * 256 + n0 + ln15) << 3);
#pragma unroll
    for (int ks = 0; ks < 5; ks++) {
        short8 a = *(const short8*)&lds[(m0 + ln15) * ST + ks * 32 + quad * 8];
        const u16* wb = wbbase + ((size_t)ks * 4 * 256 * 8);
#pragma unroll
        for (int nt = 0; nt < 8; nt++) {
            short8 b = *(const short8*)(wb + (nt << 7));
            acc[nt] = __builtin_amdgcn_mfma_f32_16x16x32_bf16(a, b, acc[nt], 0, 0, 0);
        }
    }

    __syncthreads();   // all a-frag reads done before overwrite
#pragma unroll
    for (int nt = 0; nt < 8; nt++) {
        int c = n0 + nt * 16 + ln15;
        float qv = (n0 == 0) ? qWb[c] : 0.0f;
#pragma unroll
        for (int r = 0; r < 4; r++) {
            int row = m0 + quad * 4 + r;
            lds[row * ST + c] = f2h(acc[nt][r] + qv);   // f16 output
        }
    }
    __syncthreads();
    {
        int m  = t >> 3;
        int c0 = (t & 7) * 32;
        int gn = nblk + m;
        if (gn < N) {
            uint4 v0 = *(uint4*)&lds[m * ST + c0];
            uint4 v1 = *(uint4*)&lds[m * ST + c0 + 8];
            uint4 v2 = *(uint4*)&lds[m * ST + c0 + 16];
            uint4 v3 = *(uint4*)&lds[m * ST + c0 + 24];
            u16* dst = (c0 < 128) ? (A + (size_t)gn * EMB + c0)
                                  : (B + (size_t)gn * EMB + (c0 - 128));
            ((uint4*)dst)[0] = v0;
            ((uint4*)dst)[1] = v1;
            ((uint4*)dst)[2] = v2;
            ((uint4*)dst)[3] = v3;
        }
    }
}

// ---------------------------------------------------------------------------
// K4 sorted, 4-edge unroll: each 16-lane group handles 4 consecutive perm
// entries -> 12 gather loads in flight (MLP). perm order is h-bucketed ->
// A gathers L2-local. f16 packed math.
// ---------------------------------------------------------------------------
__global__ __launch_bounds__(256) void edge_pred_srt4(
    const u64* __restrict__ perm_e,
    const u16* __restrict__ A, const u16* __restrict__ B,
    const u16* __restrict__ Rbf, const u16* __restrict__ W2h,
    const float* __restrict__ b2, float* __restrict__ out, int E)
{
    const int t    = threadIdx.x;
    const int lane = t & 63;
    const int g    = lane >> 4;
    const int k    = lane & 15;
    const int wv   = t >> 6;
    const int i0   = (blockIdx.x * 16 + wv * 4 + g) * 4;

    const uint4 uw = *(const uint4*)(W2h + k * 8);
    const float bb = b2[0];

    u64 rec[4];
    bool val[4];
#pragma unroll
    for (int j = 0; j < 4; j++) {
        val[j] = (i0 + j) < E;
        rec[j] = val[j] ? perm_e[i0 + j] : 0;   // rec=0 -> safe node-0 loads
    }
    uint4 ua[4], ub[4], ur[4];
#pragma unroll
    for (int j = 0; j < 4; j++) {
        u32 h  = (u32)rec[j] & 0x1FFFFu;
        u32 tt = (u32)(rec[j] >> 17) & 0x1FFFFu;
        u32 r  = (u32)(rec[j] >> 34) & 0x1FFu;
        ua[j] = *(const uint4*)(A + (size_t)h * EMB + k * 8);
        ub[j] = *(const uint4*)(B + (size_t)tt * EMB + k * 8);
        ur[j] = *(const uint4*)(Rbf + (size_t)r * EMB + k * 8);
    }
    float s[4];
#pragma unroll
    for (int j = 0; j < 4; j++) s[j] = ep8(ua[j], ub[j], ur[j], uw, 0.0f);
#pragma unroll
    for (int j = 0; j < 4; j++) {
        float v = s[j];
        v += __shfl_xor(v, 1, 64);
        v += __shfl_xor(v, 2, 64);
        v += __shfl_xor(v, 4, 64);
        v += __shfl_xor(v, 8, 64);
        if (k == 0 && val[j]) out[(u32)(rec[j] >> 43)] = v + bb;
    }
}

// K4 fallback (unsorted, f16 math) when workspace can't hold dedicated perm.
__global__ __launch_bounds__(256) void edge_pred_f16(
    const int* __restrict__ h_id, const int* __restrict__ r_id,
    const int* __restrict__ t_id,
    const u16* __restrict__ A, const u16* __restrict__ B,
    const u16* __restrict__ Rbf, const u16* __restrict__ W2h,
    const float* __restrict__ b2, float* __restrict__ out, int E)
{
    const int t    = threadIdx.x;
    const int lane = t & 63;
    const int g    = lane >> 4;
    const int k    = lane & 15;
    const int wv   = t >> 6;
    const int e    = blockIdx.x * 16 + wv * 4 + g;

    const uint4 uw = *(const uint4*)(W2h + k * 8);
    float s = 0.0f;
    if (e < E) {
        const int h = h_id[e], r = r_id[e], tt = t_id[e];
        const uint4 ua = *(const uint4*)(A + (size_t)h * EMB + k * 8);
        const uint4 ub = *(const uint4*)(B + (size_t)tt * EMB + k * 8);
        const uint4 ur = *(const uint4*)(Rbf + (size_t)r * EMB + k * 8);
        s = ep8(ua, ub, ur, uw, 0.0f);
    }
    s += __shfl_xor(s, 1, 64);
    s += __shfl_xor(s, 2, 64);
    s += __shfl_xor(s, 4, 64);
    s += __shfl_xor(s, 8, 64);
    if (k == 0 && e < E) out[e] = s + b2[0];
}

// ---------------------------------------------------------------------------

extern "C" void kernel_launch(void* const* d_in, const int* in_sizes, int n_in,
                              void* d_out, int out_size, void* d_ws, size_t ws_size,
                              hipStream_t stream)
{
    const int*   h_id  = (const int*)d_in[0];
    const int*   r_id  = (const int*)d_in[1];
    const int*   t_id  = (const int*)d_in[2];
    const float* q_emb = (const float*)d_in[3];
    const float* ent   = (const float*)d_in[4];
    const float* rel   = (const float*)d_in[6];
    const float* topic = (const float*)d_in[7];
    const float* nte   = (const float*)d_in[8];
    const float* W1    = (const float*)d_in[9];
    const float* b1    = (const float*)d_in[10];
    const float* W2    = (const float*)d_in[11];
    const float* b2    = (const float*)d_in[12];

    const int E    = in_sizes[0];
    const int NT   = in_sizes[4] / EMB;  // 80000 text entities
    const int N    = in_sizes[7] / 2;    // 100000 total nodes
    const int NREL = in_sizes[6] / EMB;  // 500 relations

    const int NBKT = (N + BNODES - 1) >> BSH;      // 391
    const int NSB  = (E + EPB - 1) / EPB;          // 196

    // persistent layout: [qWb][W2h][Rbf][WBF][dde1..4][Aw][Bw][perm_e?]
    float* qWb  = (float*)d_ws;                      // 128 f32
    u16* W2h    = (u16*)(qWb + EMB);                 // 128 f16
    u16* Rbf    = W2h + EMB;                         // NREL*128 f16
    u16* WBF    = Rbf + (size_t)NREL * EMB;          // KP*256 bf16
    float* dde1f = (float*)(WBF + (size_t)KP * 256); // N float2
    float* dde2f = dde1f + 2 * (size_t)N;
    float* dde3f = dde2f + 2 * (size_t)N;
    float* dde4f = dde3f + 2 * (size_t)N;
    u16* Aw = (u16*)(dde4f + 2 * (size_t)N);         // N*128 f16
    u16* Bw = Aw + (size_t)N * EMB;                  // N*128 f16
    u64* perm_ded = (u64*)(Bw + (size_t)N * EMB);    // E u64 (sorted path)

    // sort scratch aliased into Aw/Bw (dead before k2b_node writes A/B)
    u32* hist   = (u32*)Aw;                          // 2*NBKT*NSB
    u32* tot    = hist + (size_t)2 * NBKT * NSB;     // 2*NBKT
    u32* base   = tot + 2 * NBKT;                    // 2*NBKT
    u32* bstart = base + 2 * NBKT;                   // 2*(NBKT+1)
    u32* perm_t = bstart + 2 * (NBKT + 1);           // E
    u64* perm_alias = (u64*)(((size_t)(perm_t + E) + 7) & ~(size_t)7);

    size_t need_srt = (size_t)((char*)(perm_ded + E) - (char*)d_ws);
    const bool srt = (ws_size >= need_srt) && (E < (1 << 20)) &&
                     (N <= (1 << 17)) && (NREL <= (1 << 9)) &&
                     (NSB <= 256) && (2 * NBKT <= 1024);
    u64* perm_e = srt ? perm_ded : perm_alias;

    const int nn = (N + 31) / 32;

    // ---- counting sort (both directions), zero global atomics ----
    khist<<<NSB, 1024, 0, stream>>>(h_id, t_id, hist, E, NBKT, NSB);
    kscanA<<<2 * NBKT, 256, 0, stream>>>(hist, tot, NSB);
    kbase<<<1, 1024, 0, stream>>>(tot, base, bstart, NBKT, E);
    kplace<<<NSB, 1024, 0, stream>>>(h_id, r_id, t_id, hist, base,
                                     perm_t, perm_e, E, NBKT, NSB);

    // ---- scatter round 1 (+ prep) ----
    kscat<1><<<2 * NBKT + KP + 1 + NREL, 256, 0, stream>>>(
        perm_t, perm_e, bstart, topic, nullptr, nullptr, dde1f, dde3f,
        W1, q_emb, rel, b1, W2, WBF, qWb, W2h, Rbf, N, NBKT, NREL);

    // ---- scatter round 2 ----
    kscat<2><<<2 * NBKT, 256, 0, stream>>>(
        perm_t, perm_e, bstart, topic, dde1f, dde3f, dde2f, dde4f,
        W1, q_emb, rel, b1, W2, WBF, qWb, W2h, Rbf, N, NBKT, NREL);

    // ---- node GEMM (overwrites sort scratch; outputs f16 A/B) ----
    k2b_node<<<nn, 256, 0, stream>>>(
        ent, nte, topic, dde1f, dde2f, dde3f, dde4f,
        WBF, qWb, Aw, Bw, NT, N);

    // ---- edge prediction ----
    if (srt) {
        edge_pred_srt4<<<(E + 63) / 64, 256, 0, stream>>>(
            perm_e, Aw, Bw, Rbf, W2h, b2, (float*)d_out, E);
    } else {
        edge_pred_f16<<<(E + 15) / 16, 256, 0, stream>>>(
            h_id, r_id, t_id, Aw, Bw, Rbf, W2h, b2, (float*)d_out, E);
    }
}